// Round 2
// baseline (13023.860 us; speedup 1.0000x reference)
//
#include <hip/hip_runtime.h>
#include <hip/hip_bf16.h>

// DHHT hyperbolic linear-attention block — chunked low-workspace fp32 baseline.
//
// Math folding: out = [phi_q*inv_den ; vs] @ W2 + bias2, where
//   W2 rows h*512+m     : ktv_h @ F_h^T     (ktv-dependent, pass B weight)
//   W2 rows h*512+256+i : G_h = vmw^T F_h^T (ktv-independent, pass A weight)
//   bias2 = fb + vmb-through-F
// Pass A (per 4096-row chunk): proj K,V -> chunk bufs; colsum+= ; ktv+= ;
//   out_xs = vs @ G  (partial, written to d_out spatial slots)
// Pass B (per chunk): proj Q; inv_den; out += phi_q*inv_den @ W2_upper + bias2; lift.
// Workspace: ~38 MB total.

#define EPSF 1e-6f
#define CHUNK 4096
#define NCH 8

__device__ __forceinline__ float b2f(unsigned short u) {
    union { unsigned int i; float f; } c;
    c.i = ((unsigned int)u) << 16;
    return c.f;
}
__device__ __forceinline__ unsigned short f2b(float f) {
    __hip_bfloat16 h = __float2bfloat16(f);
    union { __hip_bfloat16 h; unsigned short u; } c;
    c.h = h;
    return c.u;
}

__global__ void zero_kernel(float* __restrict__ p, int n) {
    int i = blockIdx.x * 256 + threadIdx.x;
    if (i < n) p[i] = 0.f;
}

// ---------------- chunk projection: K (phi + colsum) and V ----------------
__global__ __launch_bounds__(256) void projkv_kernel(
    const float* __restrict__ X,              // source chunk base (rows*257)
    const float* __restrict__ Wk, const float* __restrict__ Bk,
    const float* __restrict__ Wv, const float* __restrict__ Bv,
    const float* __restrict__ nsc,
    unsigned short* __restrict__ phiK,        // [CHUNK][2048]
    unsigned short* __restrict__ vsb,         // [CHUNK][2048]
    float* __restrict__ colsum)               // [2048] accum
{
    const int t = threadIdx.x;
    const int job = blockIdx.y;      // 0..15
    const int mat = job >> 3;        // 0=K 1=V
    const int h = job & 7;
    const int n0 = blockIdx.x * 32;  // local row

    const float* W  = ((mat == 0) ? Wk : Wv) + (size_t)h * 256 * 257;
    const float* Bp = ((mat == 0) ? Bk : Bv) + h * 256;

    __shared__ __align__(16) float xlds[16][36];
    __shared__ float wlds[256][17];
    __shared__ float red2[32], red4[32];

    float acc[32];
#pragma unroll
    for (int r = 0; r < 32; ++r) acc[r] = 0.f;

    const int ar = t >> 3;
    const int ak = (t & 7) * 2;
    const int wk = t & 15;
    const int wo = (t >> 4) * 16;

    for (int k0 = 0; k0 < 257; k0 += 16) {
        {
            int g = k0 + ak;
            float v0 = (g < 257) ? X[(size_t)(n0 + ar) * 257 + g] : 0.f;
            float v1 = (g + 1 < 257) ? X[(size_t)(n0 + ar) * 257 + g + 1] : 0.f;
            xlds[ak][ar] = v0;
            xlds[ak + 1][ar] = v1;
        }
        {
            int g = k0 + wk;
            bool ok = (g < 257);
#pragma unroll
            for (int j = 0; j < 16; ++j)
                wlds[wo + j][wk] = ok ? W[(size_t)(wo + j) * 257 + g] : 0.f;
        }
        __syncthreads();
#pragma unroll
        for (int kk = 0; kk < 16; ++kk) {
            float bv = wlds[t][kk];
            const float4* xr = (const float4*)(&xlds[kk][0]);
#pragma unroll
            for (int g = 0; g < 8; ++g) {
                float4 xv = xr[g];
                acc[g * 4 + 0] = fmaf(xv.x, bv, acc[g * 4 + 0]);
                acc[g * 4 + 1] = fmaf(xv.y, bv, acc[g * 4 + 1]);
                acc[g * 4 + 2] = fmaf(xv.z, bv, acc[g * 4 + 2]);
                acc[g * 4 + 3] = fmaf(xv.w, bv, acc[g * 4 + 3]);
            }
        }
        __syncthreads();
    }

    const float bias = Bp[t];

    if (mat == 1) {
#pragma unroll
        for (int r = 0; r < 32; ++r)
            vsb[(size_t)(n0 + r) * 2048 + h * 256 + t] = f2b(acc[r] + bias);
        return;
    }

    // phi(u) with u = relu(xs)+EPS: phi = ||u|| * u^2 / (c * ||u^2||)
    const float c = fabsf(nsc[0]) + EPSF;
    if (t < 32) { red2[t] = 0.f; red4[t] = 0.f; }
    __syncthreads();
    const int lane = t & 63;
#pragma unroll
    for (int r = 0; r < 32; ++r) {
        float u = fmaxf(acc[r] + bias, 0.f) + EPSF;
        acc[r] = u;
        float s2 = u * u;
        float s4 = s2 * s2;
#pragma unroll
        for (int off = 32; off > 0; off >>= 1) {
            s2 += __shfl_down(s2, off, 64);
            s4 += __shfl_down(s4, off, 64);
        }
        if (lane == 0) { atomicAdd(&red2[r], s2); atomicAdd(&red4[r], s4); }
    }
    __syncthreads();
    const float inv_c = 1.0f / c;
    float csum = 0.f;
#pragma unroll
    for (int r = 0; r < 32; ++r) {
        float u = acc[r];
        float phi = u * u * sqrtf(red2[r]) * inv_c / sqrtf(red4[r]);
        phiK[(size_t)(n0 + r) * 2048 + h * 256 + t] = f2b(phi);
        csum += phi;
    }
    atomicAdd(&colsum[h * 256 + t], csum);
}

// ---------------- chunk projection: Q (phi) ----------------
__global__ __launch_bounds__(256) void projq_kernel(
    const float* __restrict__ X,              // query chunk base
    const float* __restrict__ Wq, const float* __restrict__ Bq,
    const float* __restrict__ nsc,
    unsigned short* __restrict__ phiQ)        // [CHUNK][2048]
{
    const int t = threadIdx.x;
    const int h = blockIdx.y;
    const int n0 = blockIdx.x * 32;

    const float* W  = Wq + (size_t)h * 256 * 257;
    const float* Bp = Bq + h * 256;

    __shared__ __align__(16) float xlds[16][36];
    __shared__ float wlds[256][17];
    __shared__ float red2[32], red4[32];

    float acc[32];
#pragma unroll
    for (int r = 0; r < 32; ++r) acc[r] = 0.f;

    const int ar = t >> 3;
    const int ak = (t & 7) * 2;
    const int wk = t & 15;
    const int wo = (t >> 4) * 16;

    for (int k0 = 0; k0 < 257; k0 += 16) {
        {
            int g = k0 + ak;
            float v0 = (g < 257) ? X[(size_t)(n0 + ar) * 257 + g] : 0.f;
            float v1 = (g + 1 < 257) ? X[(size_t)(n0 + ar) * 257 + g + 1] : 0.f;
            xlds[ak][ar] = v0;
            xlds[ak + 1][ar] = v1;
        }
        {
            int g = k0 + wk;
            bool ok = (g < 257);
#pragma unroll
            for (int j = 0; j < 16; ++j)
                wlds[wo + j][wk] = ok ? W[(size_t)(wo + j) * 257 + g] : 0.f;
        }
        __syncthreads();
#pragma unroll
        for (int kk = 0; kk < 16; ++kk) {
            float bv = wlds[t][kk];
            const float4* xr = (const float4*)(&xlds[kk][0]);
#pragma unroll
            for (int g = 0; g < 8; ++g) {
                float4 xv = xr[g];
                acc[g * 4 + 0] = fmaf(xv.x, bv, acc[g * 4 + 0]);
                acc[g * 4 + 1] = fmaf(xv.y, bv, acc[g * 4 + 1]);
                acc[g * 4 + 2] = fmaf(xv.z, bv, acc[g * 4 + 2]);
                acc[g * 4 + 3] = fmaf(xv.w, bv, acc[g * 4 + 3]);
            }
        }
        __syncthreads();
    }

    const float bias = Bp[t];
    const float c = fabsf(nsc[0]) + EPSF;
    if (t < 32) { red2[t] = 0.f; red4[t] = 0.f; }
    __syncthreads();
    const int lane = t & 63;
#pragma unroll
    for (int r = 0; r < 32; ++r) {
        float u = fmaxf(acc[r] + bias, 0.f) + EPSF;
        acc[r] = u;
        float s2 = u * u;
        float s4 = s2 * s2;
#pragma unroll
        for (int off = 32; off > 0; off >>= 1) {
            s2 += __shfl_down(s2, off, 64);
            s4 += __shfl_down(s4, off, 64);
        }
        if (lane == 0) { atomicAdd(&red2[r], s2); atomicAdd(&red4[r], s4); }
    }
    __syncthreads();
    const float inv_c = 1.0f / c;
#pragma unroll
    for (int r = 0; r < 32; ++r) {
        float u = acc[r];
        float phi = u * u * sqrtf(red2[r]) * inv_c / sqrtf(red4[r]);
        phiQ[(size_t)(n0 + r) * 2048 + h * 256 + t] = f2b(phi);
    }
}

// ---------------- ktv accumulate: ktv[h] += phiK_h^T @ vs_h (chunk) ----------------
__global__ __launch_bounds__(256) void ktv_kernel(
    const unsigned short* __restrict__ phiK,
    const unsigned short* __restrict__ vsb,
    float* __restrict__ ktv)
{
    const int h = blockIdx.y;
    const int sub = blockIdx.x & 3;        // 4 x 1024 rows
    const int tile = blockIdx.x >> 2;      // 2x2 of 128x128
    const int m0 = (tile >> 1) * 128;
    const int d0 = (tile & 1) * 128;
    const int t = threadIdx.x;
    const int tr = t >> 4, tc = t & 15;

    __shared__ __align__(16) float a_lds[16][128];
    __shared__ __align__(16) float b_lds[16][128];

    float acc[8][8];
#pragma unroll
    for (int i = 0; i < 8; ++i)
#pragma unroll
        for (int j = 0; j < 8; ++j) acc[i][j] = 0.f;

    const int li = t >> 4;
    const int lc = (t & 15) * 8;
    const int nbeg = sub * 1024;

    for (int n0 = nbeg; n0 < nbeg + 1024; n0 += 16) {
        {
            const ushort4* pa = (const ushort4*)(phiK + (size_t)(n0 + li) * 2048 + h * 256 + m0 + lc);
            const ushort4* pb = (const ushort4*)(vsb  + (size_t)(n0 + li) * 2048 + h * 256 + d0 + lc);
            ushort4 a0 = pa[0], a1 = pa[1];
            ushort4 b0 = pb[0], b1 = pb[1];
            a_lds[li][lc + 0] = b2f(a0.x); a_lds[li][lc + 1] = b2f(a0.y);
            a_lds[li][lc + 2] = b2f(a0.z); a_lds[li][lc + 3] = b2f(a0.w);
            a_lds[li][lc + 4] = b2f(a1.x); a_lds[li][lc + 5] = b2f(a1.y);
            a_lds[li][lc + 6] = b2f(a1.z); a_lds[li][lc + 7] = b2f(a1.w);
            b_lds[li][lc + 0] = b2f(b0.x); b_lds[li][lc + 1] = b2f(b0.y);
            b_lds[li][lc + 2] = b2f(b0.z); b_lds[li][lc + 3] = b2f(b0.w);
            b_lds[li][lc + 4] = b2f(b1.x); b_lds[li][lc + 5] = b2f(b1.y);
            b_lds[li][lc + 6] = b2f(b1.z); b_lds[li][lc + 7] = b2f(b1.w);
        }
        __syncthreads();
#pragma unroll
        for (int kk = 0; kk < 16; ++kk) {
            const float4* ap = (const float4*)(&a_lds[kk][tr * 8]);
            const float4* bp = (const float4*)(&b_lds[kk][tc * 8]);
            float4 a0 = ap[0], a1 = ap[1];
            float4 b0 = bp[0], b1 = bp[1];
            float av[8] = {a0.x, a0.y, a0.z, a0.w, a1.x, a1.y, a1.z, a1.w};
            float bv[8] = {b0.x, b0.y, b0.z, b0.w, b1.x, b1.y, b1.z, b1.w};
#pragma unroll
            for (int i = 0; i < 8; ++i)
#pragma unroll
                for (int j = 0; j < 8; ++j)
                    acc[i][j] = fmaf(av[i], bv[j], acc[i][j]);
        }
        __syncthreads();
    }
#pragma unroll
    for (int i = 0; i < 8; ++i)
#pragma unroll
        for (int j = 0; j < 8; ++j)
            atomicAdd(&ktv[((size_t)h * 256 + m0 + tr * 8 + i) * 256 + d0 + tc * 8 + j],
                      acc[i][j]);
}

// ---------------- W2 lower (G) + bias2 ----------------
__global__ __launch_bounds__(256) void w2g_kernel(
    const float* __restrict__ vmw, const float* __restrict__ vmb,
    const float* __restrict__ fw,  const float* __restrict__ fb,
    float* __restrict__ W2, float* __restrict__ bias2)
{
    const int t = threadIdx.x;
    if (blockIdx.x == 64) {
        float s = fb[t];
        for (int j = 0; j < 2048; ++j) s += vmb[j & 255] * fw[(size_t)t * 2048 + j];
        bias2[t] = s;
        return;
    }
    const int h = blockIdx.x >> 3;
    const int i0 = (blockIdx.x & 7) * 32;

    __shared__ __align__(16) float xlds[16][36];
    __shared__ float wlds[256][17];

    float acc[32];
#pragma unroll
    for (int r = 0; r < 32; ++r) acc[r] = 0.f;

    const int ar = t >> 3;
    const int ak = (t & 7) * 2;
    const int wk = t & 15;
    const int wo = (t >> 4) * 16;

    for (int d0 = 0; d0 < 256; d0 += 16) {
        xlds[ak][ar]     = vmw[(size_t)(d0 + ak) * 256 + i0 + ar];
        xlds[ak + 1][ar] = vmw[(size_t)(d0 + ak + 1) * 256 + i0 + ar];
#pragma unroll
        for (int j = 0; j < 16; ++j)
            wlds[wo + j][wk] = fw[(size_t)(wo + j) * 2048 + h * 256 + d0 + wk];
        __syncthreads();
#pragma unroll
        for (int kk = 0; kk < 16; ++kk) {
            float bv = wlds[t][kk];
            const float4* xr = (const float4*)(&xlds[kk][0]);
#pragma unroll
            for (int g = 0; g < 8; ++g) {
                float4 xv = xr[g];
                acc[g * 4 + 0] = fmaf(xv.x, bv, acc[g * 4 + 0]);
                acc[g * 4 + 1] = fmaf(xv.y, bv, acc[g * 4 + 1]);
                acc[g * 4 + 2] = fmaf(xv.z, bv, acc[g * 4 + 2]);
                acc[g * 4 + 3] = fmaf(xv.w, bv, acc[g * 4 + 3]);
            }
        }
        __syncthreads();
    }
#pragma unroll
    for (int r = 0; r < 32; ++r)
        W2[(size_t)(h * 512 + 256 + i0 + r) * 256 + t] = acc[r];
}

// ---------------- W2 upper = ktv_h @ F_h^T ----------------
__global__ __launch_bounds__(256) void w2u_kernel(
    const float* __restrict__ ktv,
    const float* __restrict__ fw,
    float* __restrict__ W2)
{
    const int t = threadIdx.x;
    const int h = blockIdx.x >> 3;
    const int m0 = (blockIdx.x & 7) * 32;

    __shared__ __align__(16) float xlds[16][36];
    __shared__ float wlds[256][17];

    float acc[32];
#pragma unroll
    for (int r = 0; r < 32; ++r) acc[r] = 0.f;

    const int ar = t >> 3;
    const int ak = (t & 7) * 2;
    const int wk = t & 15;
    const int wo = (t >> 4) * 16;

    for (int d0 = 0; d0 < 256; d0 += 16) {
        {
            const float* src = ktv + (size_t)(h * 256 + m0 + ar) * 256 + d0 + ak;
            xlds[ak][ar]     = src[0];
            xlds[ak + 1][ar] = src[1];
        }
#pragma unroll
        for (int j = 0; j < 16; ++j)
            wlds[wo + j][wk] = fw[(size_t)(wo + j) * 2048 + h * 256 + d0 + wk];
        __syncthreads();
#pragma unroll
        for (int kk = 0; kk < 16; ++kk) {
            float bv = wlds[t][kk];
            const float4* xr = (const float4*)(&xlds[kk][0]);
#pragma unroll
            for (int g = 0; g < 8; ++g) {
                float4 xv = xr[g];
                acc[g * 4 + 0] = fmaf(xv.x, bv, acc[g * 4 + 0]);
                acc[g * 4 + 1] = fmaf(xv.y, bv, acc[g * 4 + 1]);
                acc[g * 4 + 2] = fmaf(xv.z, bv, acc[g * 4 + 2]);
                acc[g * 4 + 3] = fmaf(xv.w, bv, acc[g * 4 + 3]);
            }
        }
        __syncthreads();
    }
#pragma unroll
    for (int r = 0; r < 32; ++r)
        W2[(size_t)(h * 512 + m0 + r) * 256 + t] = acc[r];
}

// ---------------- pass A output partial: out_xs = vs @ G ----------------
__global__ __launch_bounds__(256) void vsg_kernel(
    const unsigned short* __restrict__ vsb,   // chunk [4096][2048]
    const float* __restrict__ W2,
    float* __restrict__ outp)                 // chunk base (rows*257)
{
    const int t = threadIdx.x;
    const int n0 = blockIdx.x * 64;

    __shared__ __align__(16) float alds[16][68];
    __shared__ float blds[16][257];

    float acc[64];
#pragma unroll
    for (int r = 0; r < 64; ++r) acc[r] = 0.f;

    const int ar = t >> 2;
    const int kb = (t & 3) * 4;

    for (int k0 = 0; k0 < 2048; k0 += 16) {
        const int hh = k0 >> 8;
        {
            ushort4 uv = *(const ushort4*)(vsb + (size_t)(n0 + ar) * 2048 + k0 + kb);
            alds[kb + 0][ar] = b2f(uv.x);
            alds[kb + 1][ar] = b2f(uv.y);
            alds[kb + 2][ar] = b2f(uv.z);
            alds[kb + 3][ar] = b2f(uv.w);
        }
#pragma unroll
        for (int j = 0; j < 16; ++j)
            blds[j][t] = W2[(size_t)(hh * 512 + 256 + (k0 & 255) + j) * 256 + t];
        __syncthreads();
#pragma unroll
        for (int kk = 0; kk < 16; ++kk) {
            float bv = blds[kk][t];
            const float4* xr = (const float4*)(&alds[kk][0]);
#pragma unroll
            for (int g = 0; g < 16; ++g) {
                float4 xv = xr[g];
                acc[g * 4 + 0] = fmaf(xv.x, bv, acc[g * 4 + 0]);
                acc[g * 4 + 1] = fmaf(xv.y, bv, acc[g * 4 + 1]);
                acc[g * 4 + 2] = fmaf(xv.z, bv, acc[g * 4 + 2]);
                acc[g * 4 + 3] = fmaf(xv.w, bv, acc[g * 4 + 3]);
            }
        }
        __syncthreads();
    }
#pragma unroll
    for (int r = 0; r < 64; ++r)
        outp[(size_t)(n0 + r) * 257 + 1 + t] = acc[r];
}

// ---------------- inv_den per chunk ----------------
__global__ __launch_bounds__(256) void denc_kernel(
    const unsigned short* __restrict__ phiQ,  // chunk
    const float* __restrict__ colsum,
    float* __restrict__ invden)               // [CHUNK*8]
{
    const int idx = blockIdx.x * 4 + (threadIdx.x >> 6);
    const int lane = threadIdx.x & 63;
    const int n = idx >> 3, h = idx & 7;
    float s = 0.f;
#pragma unroll
    for (int j = 0; j < 4; ++j) {
        int d = lane + j * 64;
        s += b2f(phiQ[(size_t)n * 2048 + h * 256 + d]) * colsum[h * 256 + d];
    }
#pragma unroll
    for (int off = 32; off > 0; off >>= 1) s += __shfl_down(s, off, 64);
    if (lane == 0) invden[idx] = 1.f / (s + EPSF);
}

// ---------------- pass B: out += phi_q*inv_den @ W2_upper + bias2; lift ----------------
__global__ __launch_bounds__(256) void finalq_kernel(
    const unsigned short* __restrict__ phiQ,  // chunk
    const float* __restrict__ invden,         // chunk
    const float* __restrict__ W2,
    const float* __restrict__ bias2,
    float* __restrict__ outp)                 // chunk base
{
    const int t = threadIdx.x;
    const int n0 = blockIdx.x * 64;

    __shared__ __align__(16) float alds[16][68];
    __shared__ float blds[16][257];
    __shared__ float red[64];

    float acc[64];
#pragma unroll
    for (int r = 0; r < 64; ++r) acc[r] = 0.f;

    const int ar = t >> 2;
    const int kb = (t & 3) * 4;

    for (int k0 = 0; k0 < 2048; k0 += 16) {
        const int hh = k0 >> 8;
        {
            ushort4 uv = *(const ushort4*)(phiQ + (size_t)(n0 + ar) * 2048 + k0 + kb);
            float scale = invden[(n0 + ar) * 8 + hh];
            alds[kb + 0][ar] = b2f(uv.x) * scale;
            alds[kb + 1][ar] = b2f(uv.y) * scale;
            alds[kb + 2][ar] = b2f(uv.z) * scale;
            alds[kb + 3][ar] = b2f(uv.w) * scale;
        }
#pragma unroll
        for (int j = 0; j < 16; ++j)
            blds[j][t] = W2[(size_t)(hh * 512 + (k0 & 255) + j) * 256 + t];
        __syncthreads();
#pragma unroll
        for (int kk = 0; kk < 16; ++kk) {
            float bv = blds[kk][t];
            const float4* xr = (const float4*)(&alds[kk][0]);
#pragma unroll
            for (int g = 0; g < 16; ++g) {
                float4 xv = xr[g];
                acc[g * 4 + 0] = fmaf(xv.x, bv, acc[g * 4 + 0]);
                acc[g * 4 + 1] = fmaf(xv.y, bv, acc[g * 4 + 1]);
                acc[g * 4 + 2] = fmaf(xv.z, bv, acc[g * 4 + 2]);
                acc[g * 4 + 3] = fmaf(xv.w, bv, acc[g * 4 + 3]);
            }
        }
        __syncthreads();
    }

    const float bias = bias2[t];
#pragma unroll
    for (int r = 0; r < 64; ++r)
        acc[r] += bias + outp[(size_t)(n0 + r) * 257 + 1 + t];

    if (t < 64) red[t] = 0.f;
    __syncthreads();
    const int lane = t & 63;
#pragma unroll
    for (int r = 0; r < 64; ++r) {
        float s = acc[r] * acc[r];
#pragma unroll
        for (int off = 32; off > 0; off >>= 1) s += __shfl_down(s, off, 64);
        if (lane == 0) atomicAdd(&red[r], s);
    }
    __syncthreads();
#pragma unroll
    for (int r = 0; r < 64; ++r)
        outp[(size_t)(n0 + r) * 257 + 1 + t] = acc[r];
    if (t < 64) outp[(size_t)(n0 + t) * 257] = sqrtf(red[t] + 1.0f);
}

extern "C" void kernel_launch(void* const* d_in, const int* in_sizes, int n_in,
                              void* d_out, int out_size, void* d_ws, size_t ws_size,
                              hipStream_t stream)
{
    const float* xq  = (const float*)d_in[0];
    const float* xs  = (const float*)d_in[1];
    const float* Wq  = (const float*)d_in[2];
    const float* Bq  = (const float*)d_in[3];
    const float* Wk  = (const float*)d_in[4];
    const float* Bk  = (const float*)d_in[5];
    const float* Wv  = (const float*)d_in[6];
    const float* Bv  = (const float*)d_in[7];
    const float* nsc = (const float*)d_in[8];
    const float* vmw = (const float*)d_in[9];
    const float* vmb = (const float*)d_in[10];
    const float* fw  = (const float*)d_in[11];
    const float* fb  = (const float*)d_in[12];
    float* outp = (float*)d_out;

    char* ws = (char*)d_ws;
    // workspace layout (bytes), total ~38.1 MB
    float* ktv    = (float*)(ws + 0);              // 2,097,152
    float* colsum = (float*)(ws + 2097152);        //     8,192 (contiguous w/ ktv for zeroing)
    float* W2     = (float*)(ws + 2105344);        // 4,194,304
    float* bias2  = (float*)(ws + 6299648);        //     1,024
    float* invden = (float*)(ws + 6300672);        //   131,072
    unsigned short* bufA = (unsigned short*)(ws + 6431744);   // 16,777,216
    unsigned short* bufB = (unsigned short*)(ws + 23208960);  // 16,777,216

    // zero ktv + colsum (contiguous 526336 floats)
    zero_kernel<<<dim3(2056), 256, 0, stream>>>(ktv, 526336);
    // ktv-independent weights
    w2g_kernel<<<dim3(65), 256, 0, stream>>>(vmw, vmb, fw, fb, W2, bias2);

    // Pass A: K/V chunks -> colsum, ktv, vs@G partial into d_out
    for (int c = 0; c < NCH; ++c) {
        const float* xs_c = xs + (size_t)c * CHUNK * 257;
        float* out_c = outp + (size_t)c * CHUNK * 257;
        projkv_kernel<<<dim3(128, 16), 256, 0, stream>>>(
            xs_c, Wk, Bk, Wv, Bv, nsc, bufA, bufB, colsum);
        ktv_kernel<<<dim3(16, 8), 256, 0, stream>>>(bufA, bufB, ktv);
        vsg_kernel<<<dim3(64), 256, 0, stream>>>(bufB, W2, out_c);
    }

    // ktv-dependent weights
    w2u_kernel<<<dim3(64), 256, 0, stream>>>(ktv, fw, W2);

    // Pass B: Q chunks -> inv_den, final output + lift
    for (int c = 0; c < NCH; ++c) {
        const float* xq_c = xq + (size_t)c * CHUNK * 257;
        float* out_c = outp + (size_t)c * CHUNK * 257;
        projq_kernel<<<dim3(128, 8), 256, 0, stream>>>(xq_c, Wq, Bq, nsc, bufA);
        denc_kernel<<<dim3(8192), 256, 0, stream>>>(bufA, colsum, invden);
        finalq_kernel<<<dim3(64), 256, 0, stream>>>(bufA, invden, W2, bias2, out_c);
    }
}

// Round 3
// 5923.940 us; speedup vs baseline: 2.1985x; 2.1985x over previous
//
#include <hip/hip_runtime.h>
#include <hip/hip_bf16.h>

// DHHT hyperbolic linear-attention block — round 3: parallelism fix.
// vsg/finalq (grid-64, 3% occupancy, 698 us each) replaced by split-K
// gemm_acc (grid 1024, atomicAdd fp32 into d_out) + lift epilogue.
// ktv split 2x more (grid 256). Everything else carried from round 2.
//
// Math folding: out_spatial = [phi_q*inv_den ; vs] @ W2 + bias2, where
//   W2 rows h*512+m     : ktv_h @ F_h^T     (pass B weight)
//   W2 rows h*512+256+i : G_h = vmw^T F_h^T (pass A weight)
//   bias2 = fb + vmb-through-F

#define EPSF 1e-6f
#define CHUNK 4096
#define NCH 8

__device__ __forceinline__ float b2f(unsigned short u) {
    union { unsigned int i; float f; } c;
    c.i = ((unsigned int)u) << 16;
    return c.f;
}
__device__ __forceinline__ unsigned short f2b(float f) {
    __hip_bfloat16 h = __float2bfloat16(f);
    union { __hip_bfloat16 h; unsigned short u; } c;
    c.h = h;
    return c.u;
}

__global__ void zero_kernel(float* __restrict__ p, int n) {
    int i = blockIdx.x * 256 + threadIdx.x;
    if (i < n) p[i] = 0.f;
}

// ---------------- chunk projection: K (phi + colsum) and V ----------------
__global__ __launch_bounds__(256) void projkv_kernel(
    const float* __restrict__ X,
    const float* __restrict__ Wk, const float* __restrict__ Bk,
    const float* __restrict__ Wv, const float* __restrict__ Bv,
    const float* __restrict__ nsc,
    unsigned short* __restrict__ phiK,
    unsigned short* __restrict__ vsb,
    float* __restrict__ colsum)
{
    const int t = threadIdx.x;
    const int job = blockIdx.y;      // 0..15
    const int mat = job >> 3;        // 0=K 1=V
    const int h = job & 7;
    const int n0 = blockIdx.x * 32;

    const float* W  = ((mat == 0) ? Wk : Wv) + (size_t)h * 256 * 257;
    const float* Bp = ((mat == 0) ? Bk : Bv) + h * 256;

    __shared__ __align__(16) float xlds[16][40];
    __shared__ float wlds[256][17];
    __shared__ float red2[32], red4[32];

    float acc[32];
#pragma unroll
    for (int r = 0; r < 32; ++r) acc[r] = 0.f;

    const int ar = t >> 3;
    const int ak = (t & 7) * 2;
    const int wk = t & 15;
    const int wo = (t >> 4) * 16;

    for (int k0 = 0; k0 < 257; k0 += 16) {
        {
            int g = k0 + ak;
            float v0 = (g < 257) ? X[(size_t)(n0 + ar) * 257 + g] : 0.f;
            float v1 = (g + 1 < 257) ? X[(size_t)(n0 + ar) * 257 + g + 1] : 0.f;
            xlds[ak][ar] = v0;
            xlds[ak + 1][ar] = v1;
        }
        {
            int g = k0 + wk;
            bool ok = (g < 257);
#pragma unroll
            for (int j = 0; j < 16; ++j)
                wlds[wo + j][wk] = ok ? W[(size_t)(wo + j) * 257 + g] : 0.f;
        }
        __syncthreads();
#pragma unroll
        for (int kk = 0; kk < 16; ++kk) {
            float bv = wlds[t][kk];
            const float4* xr = (const float4*)(&xlds[kk][0]);
#pragma unroll
            for (int g = 0; g < 8; ++g) {
                float4 xv = xr[g];
                acc[g * 4 + 0] = fmaf(xv.x, bv, acc[g * 4 + 0]);
                acc[g * 4 + 1] = fmaf(xv.y, bv, acc[g * 4 + 1]);
                acc[g * 4 + 2] = fmaf(xv.z, bv, acc[g * 4 + 2]);
                acc[g * 4 + 3] = fmaf(xv.w, bv, acc[g * 4 + 3]);
            }
        }
        __syncthreads();
    }

    const float bias = Bp[t];

    if (mat == 1) {
#pragma unroll
        for (int r = 0; r < 32; ++r)
            vsb[(size_t)(n0 + r) * 2048 + h * 256 + t] = f2b(acc[r] + bias);
        return;
    }

    const float c = fabsf(nsc[0]) + EPSF;
    if (t < 32) { red2[t] = 0.f; red4[t] = 0.f; }
    __syncthreads();
    const int lane = t & 63;
#pragma unroll
    for (int r = 0; r < 32; ++r) {
        float u = fmaxf(acc[r] + bias, 0.f) + EPSF;
        acc[r] = u;
        float s2 = u * u;
        float s4 = s2 * s2;
#pragma unroll
        for (int off = 32; off > 0; off >>= 1) {
            s2 += __shfl_down(s2, off, 64);
            s4 += __shfl_down(s4, off, 64);
        }
        if (lane == 0) { atomicAdd(&red2[r], s2); atomicAdd(&red4[r], s4); }
    }
    __syncthreads();
    const float inv_c = 1.0f / c;
    float csum = 0.f;
#pragma unroll
    for (int r = 0; r < 32; ++r) {
        float u = acc[r];
        float phi = u * u * sqrtf(red2[r]) * inv_c / sqrtf(red4[r]);
        phiK[(size_t)(n0 + r) * 2048 + h * 256 + t] = f2b(phi);
        csum += phi;
    }
    atomicAdd(&colsum[h * 256 + t], csum);
}

// ---------------- chunk projection: Q (phi) ----------------
__global__ __launch_bounds__(256) void projq_kernel(
    const float* __restrict__ X,
    const float* __restrict__ Wq, const float* __restrict__ Bq,
    const float* __restrict__ nsc,
    unsigned short* __restrict__ phiQ)
{
    const int t = threadIdx.x;
    const int h = blockIdx.y;
    const int n0 = blockIdx.x * 32;

    const float* W  = Wq + (size_t)h * 256 * 257;
    const float* Bp = Bq + h * 256;

    __shared__ __align__(16) float xlds[16][40];
    __shared__ float wlds[256][17];
    __shared__ float red2[32], red4[32];

    float acc[32];
#pragma unroll
    for (int r = 0; r < 32; ++r) acc[r] = 0.f;

    const int ar = t >> 3;
    const int ak = (t & 7) * 2;
    const int wk = t & 15;
    const int wo = (t >> 4) * 16;

    for (int k0 = 0; k0 < 257; k0 += 16) {
        {
            int g = k0 + ak;
            float v0 = (g < 257) ? X[(size_t)(n0 + ar) * 257 + g] : 0.f;
            float v1 = (g + 1 < 257) ? X[(size_t)(n0 + ar) * 257 + g + 1] : 0.f;
            xlds[ak][ar] = v0;
            xlds[ak + 1][ar] = v1;
        }
        {
            int g = k0 + wk;
            bool ok = (g < 257);
#pragma unroll
            for (int j = 0; j < 16; ++j)
                wlds[wo + j][wk] = ok ? W[(size_t)(wo + j) * 257 + g] : 0.f;
        }
        __syncthreads();
#pragma unroll
        for (int kk = 0; kk < 16; ++kk) {
            float bv = wlds[t][kk];
            const float4* xr = (const float4*)(&xlds[kk][0]);
#pragma unroll
            for (int g = 0; g < 8; ++g) {
                float4 xv = xr[g];
                acc[g * 4 + 0] = fmaf(xv.x, bv, acc[g * 4 + 0]);
                acc[g * 4 + 1] = fmaf(xv.y, bv, acc[g * 4 + 1]);
                acc[g * 4 + 2] = fmaf(xv.z, bv, acc[g * 4 + 2]);
                acc[g * 4 + 3] = fmaf(xv.w, bv, acc[g * 4 + 3]);
            }
        }
        __syncthreads();
    }

    const float bias = Bp[t];
    const float c = fabsf(nsc[0]) + EPSF;
    if (t < 32) { red2[t] = 0.f; red4[t] = 0.f; }
    __syncthreads();
    const int lane = t & 63;
#pragma unroll
    for (int r = 0; r < 32; ++r) {
        float u = fmaxf(acc[r] + bias, 0.f) + EPSF;
        acc[r] = u;
        float s2 = u * u;
        float s4 = s2 * s2;
#pragma unroll
        for (int off = 32; off > 0; off >>= 1) {
            s2 += __shfl_down(s2, off, 64);
            s4 += __shfl_down(s4, off, 64);
        }
        if (lane == 0) { atomicAdd(&red2[r], s2); atomicAdd(&red4[r], s4); }
    }
    __syncthreads();
    const float inv_c = 1.0f / c;
#pragma unroll
    for (int r = 0; r < 32; ++r) {
        float u = acc[r];
        float phi = u * u * sqrtf(red2[r]) * inv_c / sqrtf(red4[r]);
        phiQ[(size_t)(n0 + r) * 2048 + h * 256 + t] = f2b(phi);
    }
}

// ---------------- ktv accumulate: ktv[h] += phiK_h^T @ vs_h (chunk) ----------------
// grid (32, 8): x = sub(8) * tile(4)
__global__ __launch_bounds__(256) void ktv_kernel(
    const unsigned short* __restrict__ phiK,
    const unsigned short* __restrict__ vsb,
    float* __restrict__ ktv)
{
    const int h = blockIdx.y;
    const int sub = blockIdx.x >> 2;       // 0..7, 512 rows each
    const int tile = blockIdx.x & 3;       // 2x2 of 128x128
    const int m0 = (tile >> 1) * 128;
    const int d0 = (tile & 1) * 128;
    const int t = threadIdx.x;
    const int tr = t >> 4, tc = t & 15;

    __shared__ __align__(16) float a_lds[16][128];
    __shared__ __align__(16) float b_lds[16][128];

    float acc[8][8];
#pragma unroll
    for (int i = 0; i < 8; ++i)
#pragma unroll
        for (int j = 0; j < 8; ++j) acc[i][j] = 0.f;

    const int li = t >> 4;
    const int lc = (t & 15) * 8;
    const int nbeg = sub * 512;

    for (int n0 = nbeg; n0 < nbeg + 512; n0 += 16) {
        {
            const ushort4* pa = (const ushort4*)(phiK + (size_t)(n0 + li) * 2048 + h * 256 + m0 + lc);
            const ushort4* pb = (const ushort4*)(vsb  + (size_t)(n0 + li) * 2048 + h * 256 + d0 + lc);
            ushort4 a0 = pa[0], a1 = pa[1];
            ushort4 b0 = pb[0], b1 = pb[1];
            a_lds[li][lc + 0] = b2f(a0.x); a_lds[li][lc + 1] = b2f(a0.y);
            a_lds[li][lc + 2] = b2f(a0.z); a_lds[li][lc + 3] = b2f(a0.w);
            a_lds[li][lc + 4] = b2f(a1.x); a_lds[li][lc + 5] = b2f(a1.y);
            a_lds[li][lc + 6] = b2f(a1.z); a_lds[li][lc + 7] = b2f(a1.w);
            b_lds[li][lc + 0] = b2f(b0.x); b_lds[li][lc + 1] = b2f(b0.y);
            b_lds[li][lc + 2] = b2f(b0.z); b_lds[li][lc + 3] = b2f(b0.w);
            b_lds[li][lc + 4] = b2f(b1.x); b_lds[li][lc + 5] = b2f(b1.y);
            b_lds[li][lc + 6] = b2f(b1.z); b_lds[li][lc + 7] = b2f(b1.w);
        }
        __syncthreads();
#pragma unroll
        for (int kk = 0; kk < 16; ++kk) {
            const float4* ap = (const float4*)(&a_lds[kk][tr * 8]);
            const float4* bp = (const float4*)(&b_lds[kk][tc * 8]);
            float4 a0 = ap[0], a1 = ap[1];
            float4 b0 = bp[0], b1 = bp[1];
            float av[8] = {a0.x, a0.y, a0.z, a0.w, a1.x, a1.y, a1.z, a1.w};
            float bv[8] = {b0.x, b0.y, b0.z, b0.w, b1.x, b1.y, b1.z, b1.w};
#pragma unroll
            for (int i = 0; i < 8; ++i)
#pragma unroll
                for (int j = 0; j < 8; ++j)
                    acc[i][j] = fmaf(av[i], bv[j], acc[i][j]);
        }
        __syncthreads();
    }
#pragma unroll
    for (int i = 0; i < 8; ++i)
#pragma unroll
        for (int j = 0; j < 8; ++j)
            atomicAdd(&ktv[((size_t)h * 256 + m0 + tr * 8 + i) * 256 + d0 + tc * 8 + j],
                      acc[i][j]);
}

// ---------------- W2 lower (G) + bias2 ----------------
__global__ __launch_bounds__(256) void w2g_kernel(
    const float* __restrict__ vmw, const float* __restrict__ vmb,
    const float* __restrict__ fw,  const float* __restrict__ fb,
    float* __restrict__ W2, float* __restrict__ bias2)
{
    const int t = threadIdx.x;
    if (blockIdx.x == 64) {
        float s = fb[t];
        for (int j = 0; j < 2048; ++j) s += vmb[j & 255] * fw[(size_t)t * 2048 + j];
        bias2[t] = s;
        return;
    }
    const int h = blockIdx.x >> 3;
    const int i0 = (blockIdx.x & 7) * 32;

    __shared__ __align__(16) float xlds[16][40];
    __shared__ float wlds[256][17];

    float acc[32];
#pragma unroll
    for (int r = 0; r < 32; ++r) acc[r] = 0.f;

    const int ar = t >> 3;
    const int ak = (t & 7) * 2;
    const int wk = t & 15;
    const int wo = (t >> 4) * 16;

    for (int d0 = 0; d0 < 256; d0 += 16) {
        xlds[ak][ar]     = vmw[(size_t)(d0 + ak) * 256 + i0 + ar];
        xlds[ak + 1][ar] = vmw[(size_t)(d0 + ak + 1) * 256 + i0 + ar];
#pragma unroll
        for (int j = 0; j < 16; ++j)
            wlds[wo + j][wk] = fw[(size_t)(wo + j) * 2048 + h * 256 + d0 + wk];
        __syncthreads();
#pragma unroll
        for (int kk = 0; kk < 16; ++kk) {
            float bv = wlds[t][kk];
            const float4* xr = (const float4*)(&xlds[kk][0]);
#pragma unroll
            for (int g = 0; g < 8; ++g) {
                float4 xv = xr[g];
                acc[g * 4 + 0] = fmaf(xv.x, bv, acc[g * 4 + 0]);
                acc[g * 4 + 1] = fmaf(xv.y, bv, acc[g * 4 + 1]);
                acc[g * 4 + 2] = fmaf(xv.z, bv, acc[g * 4 + 2]);
                acc[g * 4 + 3] = fmaf(xv.w, bv, acc[g * 4 + 3]);
            }
        }
        __syncthreads();
    }
#pragma unroll
    for (int r = 0; r < 32; ++r)
        W2[(size_t)(h * 512 + 256 + i0 + r) * 256 + t] = acc[r];
}

// ---------------- W2 upper = ktv_h @ F_h^T ----------------
__global__ __launch_bounds__(256) void w2u_kernel(
    const float* __restrict__ ktv,
    const float* __restrict__ fw,
    float* __restrict__ W2)
{
    const int t = threadIdx.x;
    const int h = blockIdx.x >> 3;
    const int m0 = (blockIdx.x & 7) * 32;

    __shared__ __align__(16) float xlds[16][40];
    __shared__ float wlds[256][17];

    float acc[32];
#pragma unroll
    for (int r = 0; r < 32; ++r) acc[r] = 0.f;

    const int ar = t >> 3;
    const int ak = (t & 7) * 2;
    const int wk = t & 15;
    const int wo = (t >> 4) * 16;

    for (int d0 = 0; d0 < 256; d0 += 16) {
        {
            const float* src = ktv + (size_t)(h * 256 + m0 + ar) * 256 + d0 + ak;
            xlds[ak][ar]     = src[0];
            xlds[ak + 1][ar] = src[1];
        }
#pragma unroll
        for (int j = 0; j < 16; ++j)
            wlds[wo + j][wk] = fw[(size_t)(wo + j) * 2048 + h * 256 + d0 + wk];
        __syncthreads();
#pragma unroll
        for (int kk = 0; kk < 16; ++kk) {
            float bv = wlds[t][kk];
            const float4* xr = (const float4*)(&xlds[kk][0]);
#pragma unroll
            for (int g = 0; g < 8; ++g) {
                float4 xv = xr[g];
                acc[g * 4 + 0] = fmaf(xv.x, bv, acc[g * 4 + 0]);
                acc[g * 4 + 1] = fmaf(xv.y, bv, acc[g * 4 + 1]);
                acc[g * 4 + 2] = fmaf(xv.z, bv, acc[g * 4 + 2]);
                acc[g * 4 + 3] = fmaf(xv.w, bv, acc[g * 4 + 3]);
            }
        }
        __syncthreads();
    }
#pragma unroll
    for (int r = 0; r < 32; ++r)
        W2[(size_t)(h * 512 + m0 + r) * 256 + t] = acc[r];
}

// ---------------- split-K chunk GEMM with atomic accumulation ----------------
// grid (128 row-tiles, 8 heads); block: 32 rows x 256 cols, k = one head slice (256)
// out[n, 1+t] += A[n, h*256 + k] * W2[h*512 + woff + k][t]
__global__ __launch_bounds__(256) void gemm_acc_kernel(
    const unsigned short* __restrict__ Abuf,  // [4096][2048] bf16
    const float* __restrict__ invden,         // per (row*8+h) scale, or nullptr
    const float* __restrict__ W2,
    int woff,                                 // 0 = ktv part, 256 = G part
    float* __restrict__ outp)                 // chunk base (rows * 257)
{
    const int t = threadIdx.x;
    const int n0 = blockIdx.x * 32;
    const int h = blockIdx.y;

    __shared__ __align__(16) float alds[16][40];
    __shared__ float blds[16][257];

    float acc[32];
#pragma unroll
    for (int r = 0; r < 32; ++r) acc[r] = 0.f;

    const int ar = t >> 3;        // 0..31 (row)
    const int ak = (t & 7) * 2;   // 0..14 (k pair)
    const float scale = invden ? invden[(n0 + ar) * 8 + h] : 1.0f;
    const float* Wbase = W2 + (size_t)(h * 512 + woff) * 256;

    for (int k0 = 0; k0 < 256; k0 += 16) {
        {
            const unsigned short* src = Abuf + (size_t)(n0 + ar) * 2048 + h * 256 + k0 + ak;
            alds[ak][ar]     = b2f(src[0]) * scale;
            alds[ak + 1][ar] = b2f(src[1]) * scale;
        }
#pragma unroll
        for (int j = 0; j < 16; ++j)
            blds[j][t] = Wbase[(size_t)(k0 + j) * 256 + t];
        __syncthreads();
#pragma unroll
        for (int kk = 0; kk < 16; ++kk) {
            float bv = blds[kk][t];
            const float4* xr = (const float4*)(&alds[kk][0]);
#pragma unroll
            for (int g = 0; g < 8; ++g) {
                float4 xv = xr[g];
                acc[g * 4 + 0] = fmaf(xv.x, bv, acc[g * 4 + 0]);
                acc[g * 4 + 1] = fmaf(xv.y, bv, acc[g * 4 + 1]);
                acc[g * 4 + 2] = fmaf(xv.z, bv, acc[g * 4 + 2]);
                acc[g * 4 + 3] = fmaf(xv.w, bv, acc[g * 4 + 3]);
            }
        }
        __syncthreads();
    }
#pragma unroll
    for (int r = 0; r < 32; ++r)
        atomicAdd(&outp[(size_t)(n0 + r) * 257 + 1 + t], acc[r]);
}

// ---------------- epilogue: bias + Lorentz lift ----------------
// grid 512 x 256: block handles 64 rows, wave w -> rows w*16..w*16+15
__global__ __launch_bounds__(256) void lift_kernel(
    const float* __restrict__ bias2, float* __restrict__ outp)
{
    const int t = threadIdx.x;
    const int lane = t & 63;
    const int w = t >> 6;
    const int n0 = blockIdx.x * 64 + w * 16;
    float b[4];
#pragma unroll
    for (int j = 0; j < 4; ++j) b[j] = bias2[lane + j * 64];
    for (int r = 0; r < 16; ++r) {
        float* row = outp + (size_t)(n0 + r) * 257;
        float v[4];
        float s = 0.f;
#pragma unroll
        for (int j = 0; j < 4; ++j) {
            v[j] = row[1 + lane + j * 64] + b[j];
            s = fmaf(v[j], v[j], s);
        }
#pragma unroll
        for (int off = 32; off > 0; off >>= 1) s += __shfl_down(s, off, 64);
#pragma unroll
        for (int j = 0; j < 4; ++j) row[1 + lane + j * 64] = v[j];
        if (lane == 0) row[0] = sqrtf(s + 1.0f);
    }
}

// ---------------- inv_den per chunk ----------------
__global__ __launch_bounds__(256) void denc_kernel(
    const unsigned short* __restrict__ phiQ,
    const float* __restrict__ colsum,
    float* __restrict__ invden)
{
    const int idx = blockIdx.x * 4 + (threadIdx.x >> 6);
    const int lane = threadIdx.x & 63;
    const int n = idx >> 3, h = idx & 7;
    float s = 0.f;
#pragma unroll
    for (int j = 0; j < 4; ++j) {
        int d = lane + j * 64;
        s += b2f(phiQ[(size_t)n * 2048 + h * 256 + d]) * colsum[h * 256 + d];
    }
#pragma unroll
    for (int off = 32; off > 0; off >>= 1) s += __shfl_down(s, off, 64);
    if (lane == 0) invden[idx] = 1.f / (s + EPSF);
}

extern "C" void kernel_launch(void* const* d_in, const int* in_sizes, int n_in,
                              void* d_out, int out_size, void* d_ws, size_t ws_size,
                              hipStream_t stream)
{
    const float* xq  = (const float*)d_in[0];
    const float* xs  = (const float*)d_in[1];
    const float* Wq  = (const float*)d_in[2];
    const float* Bq  = (const float*)d_in[3];
    const float* Wk  = (const float*)d_in[4];
    const float* Bk  = (const float*)d_in[5];
    const float* Wv  = (const float*)d_in[6];
    const float* Bv  = (const float*)d_in[7];
    const float* nsc = (const float*)d_in[8];
    const float* vmw = (const float*)d_in[9];
    const float* vmb = (const float*)d_in[10];
    const float* fw  = (const float*)d_in[11];
    const float* fb  = (const float*)d_in[12];
    float* outp = (float*)d_out;

    char* ws = (char*)d_ws;
    float* ktv    = (float*)(ws + 0);              // 2,097,152
    float* colsum = (float*)(ws + 2097152);        //     8,192 (contiguous for zeroing)
    float* W2     = (float*)(ws + 2105344);        // 4,194,304
    float* bias2  = (float*)(ws + 6299648);        //     1,024
    float* invden = (float*)(ws + 6300672);        //   131,072
    unsigned short* bufA = (unsigned short*)(ws + 6431744);   // 16,777,216
    unsigned short* bufB = (unsigned short*)(ws + 23208960);  // 16,777,216

    // zero ktv + colsum, and the full output (split-K accumulates into it)
    zero_kernel<<<dim3(2056), 256, 0, stream>>>(ktv, 526336);
    zero_kernel<<<dim3(32896), 256, 0, stream>>>(outp, 32768 * 257);
    // ktv-independent weights
    w2g_kernel<<<dim3(65), 256, 0, stream>>>(vmw, vmb, fw, fb, W2, bias2);

    // Pass A: K/V chunks -> colsum, ktv, vs@G accumulated into d_out
    for (int c = 0; c < NCH; ++c) {
        const float* xs_c = xs + (size_t)c * CHUNK * 257;
        float* out_c = outp + (size_t)c * CHUNK * 257;
        projkv_kernel<<<dim3(128, 16), 256, 0, stream>>>(
            xs_c, Wk, Bk, Wv, Bv, nsc, bufA, bufB, colsum);
        ktv_kernel<<<dim3(32, 8), 256, 0, stream>>>(bufA, bufB, ktv);
        gemm_acc_kernel<<<dim3(128, 8), 256, 0, stream>>>(
            bufB, nullptr, W2, 256, out_c);
    }

    // ktv-dependent weights
    w2u_kernel<<<dim3(64), 256, 0, stream>>>(ktv, fw, W2);

    // Pass B: Q chunks -> inv_den, phi_q*invden @ W2u accumulated into d_out
    for (int c = 0; c < NCH; ++c) {
        const float* xq_c = xq + (size_t)c * CHUNK * 257;
        float* out_c = outp + (size_t)c * CHUNK * 257;
        projq_kernel<<<dim3(128, 8), 256, 0, stream>>>(xq_c, Wq, Bq, nsc, bufA);
        denc_kernel<<<dim3(8192), 256, 0, stream>>>(bufA, colsum, invden);
        gemm_acc_kernel<<<dim3(128, 8), 256, 0, stream>>>(
            bufA, invden, W2, 0, out_c);
    }

    // bias + Lorentz lift
    lift_kernel<<<dim3(512), 256, 0, stream>>>(bias2, outp);
}

// Round 4
// 3687.786 us; speedup vs baseline: 3.5316x; 1.6064x over previous
//
#include <hip/hip_runtime.h>
#include <hip/hip_bf16.h>

// DHHT round 4: all four GEMM families converted to bf16 MFMA (16x16x32).
// K=257 zero-padded to 288. W2 stored transposed bf16 [256][6144]:
//   cols 0..2047   : W2u = ktv_h @ F_h^T          (pass B, A=phiQ*invden)
//   cols 2048..4095: G_hi                          (pass A, A=vs)
//   cols 4096..6143: G_lo = G - bf16(G_hi)         (pass A, error compensation)
// finalA plain-stores out spatial, finalB read-adds, lift adds bias2 + time.
// Chunk = 2048 rows x 16 chunks; workspace ~25.5 MB.

#define EPSF 1e-6f
#define CH 2048
#define NCHK 16

typedef __attribute__((ext_vector_type(8))) short bf16x8;
typedef __attribute__((ext_vector_type(8))) unsigned short u16x8;
typedef __attribute__((ext_vector_type(4))) float f32x4;

__device__ __forceinline__ float b2f(unsigned short u) {
    union { unsigned int i; float f; } c;
    c.i = ((unsigned int)u) << 16;
    return c.f;
}
__device__ __forceinline__ unsigned short f2b(float f) {
    __hip_bfloat16 h = __float2bfloat16(f);
    union { __hip_bfloat16 h; unsigned short u; } c;
    c.h = h;
    return c.u;
}

__global__ void zero_kernel(float* __restrict__ p, int n) {
    int i = blockIdx.x * 256 + threadIdx.x;
    if (i < n) p[i] = 0.f;
}

// ---------------- weight convert: Wbf [6144][288] bf16 + biasAll[6144] ----------------
__global__ __launch_bounds__(256) void wconv_kernel(
    const float* __restrict__ Wq, const float* __restrict__ Wk, const float* __restrict__ Wv,
    const float* __restrict__ Bq, const float* __restrict__ Bk, const float* __restrict__ Bv,
    unsigned short* __restrict__ Wbf, float* __restrict__ biasAll)
{
    const int t = threadIdx.x;
    const int b = blockIdx.x;
    if (b < 6144) {
        const int mat = b >> 11, lr = b & 2047;
        const float* Ws = (mat == 0 ? Wq : mat == 1 ? Wk : Wv) + (size_t)lr * 257;
        Wbf[(size_t)b * 288 + t] = f2b(Ws[t]);
        if (t < 32) {
            float v = (t == 0) ? Ws[256] : 0.f;
            Wbf[(size_t)b * 288 + 256 + t] = f2b(v);
        }
    } else {
        const int e = (b - 6144) * 256 + t;
        const int mat = e >> 11, r = e & 2047;
        biasAll[e] = (mat == 0 ? Bq : mat == 1 ? Bk : Bv)[r];
    }
}

// ---------------- X chunk convert: fp32 [CH][257] -> bf16 [CH][288] ----------------
__global__ __launch_bounds__(256) void xconv_kernel(
    const float* __restrict__ X, unsigned short* __restrict__ Xbf)
{
    const int t = threadIdx.x;
    const int r0 = blockIdx.x * 8;
    for (int rr = 0; rr < 8; ++rr) {
        const int r = r0 + rr;
        Xbf[(size_t)r * 288 + t] = f2b(X[(size_t)r * 257 + t]);
        if (t < 32) {
            float v = (t == 0) ? X[(size_t)r * 257 + 256] : 0.f;
            Xbf[(size_t)r * 288 + 256 + t] = f2b(v);
        }
    }
}

// ---------------- projection MFMA GEMM: [CH x 288] @ [Ncols x 288]^T ----------------
// grid (CH/128, Ncols/128). Output bf16, bias added. col < splitCol -> outA[.,col],
// else outB[., col-2048].
__global__ __launch_bounds__(256) void proj_mfma(
    const unsigned short* __restrict__ Xbf,
    const unsigned short* __restrict__ Wbase,
    const float* __restrict__ biasBase,
    unsigned short* __restrict__ outA,
    unsigned short* __restrict__ outB,
    int splitCol)
{
    __shared__ __align__(16) unsigned short lA[128 * 40];
    __shared__ __align__(16) unsigned short lB[128 * 40];
    const int t = threadIdx.x;
    const int m0 = blockIdx.x * 128;
    const int c0 = blockIdx.y * 128;
    const int lane = t & 63, w = t >> 6;
    const int wm = (w >> 1) * 64, wn = (w & 1) * 64;
    const int l15 = lane & 15, q = lane >> 4;

    f32x4 acc[4][4] = {};

    for (int ks = 0; ks < 9; ++ks) {
        const int k0 = ks * 32;
#pragma unroll
        for (int qq = 0; qq < 2; ++qq) {
            const int e = t + qq * 256;
            const int row = e >> 2, kg = (e & 3) * 8;
            *(u16x8*)(&lA[row * 40 + kg]) =
                *(const u16x8*)(Xbf + (size_t)(m0 + row) * 288 + k0 + kg);
            *(u16x8*)(&lB[row * 40 + kg]) =
                *(const u16x8*)(Wbase + (size_t)(c0 + row) * 288 + k0 + kg);
        }
        __syncthreads();
        bf16x8 af[4], bfr[4];
#pragma unroll
        for (int i = 0; i < 4; ++i)
            af[i] = *(const bf16x8*)(&lA[(wm + i * 16 + l15) * 40 + q * 8]);
#pragma unroll
        for (int j = 0; j < 4; ++j)
            bfr[j] = *(const bf16x8*)(&lB[(wn + j * 16 + l15) * 40 + q * 8]);
#pragma unroll
        for (int i = 0; i < 4; ++i)
#pragma unroll
            for (int j = 0; j < 4; ++j)
                acc[i][j] = __builtin_amdgcn_mfma_f32_16x16x32_bf16(af[i], bfr[j], acc[i][j], 0, 0, 0);
        __syncthreads();
    }

#pragma unroll
    for (int j = 0; j < 4; ++j) {
        const int cg = c0 + wn + j * 16 + l15;
        const float bias = biasBase[cg];
        unsigned short* dst;
        int cd;
        if (cg < splitCol) { dst = outA; cd = cg; }
        else               { dst = outB; cd = cg - 2048; }
#pragma unroll
        for (int i = 0; i < 4; ++i)
#pragma unroll
            for (int r = 0; r < 4; ++r) {
                const int n = m0 + wm + i * 16 + q * 4 + r;
                dst[(size_t)n * 2048 + cd] = f2b(acc[i][j][r] + bias);
            }
    }
}

// ---------------- phi (in-place on [CH][2048] bf16) ----------------
// mode 0 (K): phi + colsum accumulate.  mode 1 (Q): phi * invden (colsum read).
__global__ __launch_bounds__(256) void phi_kernel(
    unsigned short* __restrict__ buf,
    const float* __restrict__ nsc,
    float* __restrict__ colsum,
    int mode)
{
    const int t = threadIdx.x;
    const int c8 = t * 8;
    const float c = fabsf(nsc[0]) + EPSF;
    float cs[8], csum[8];
#pragma unroll
    for (int e = 0; e < 8; ++e) csum[e] = 0.f;
    if (mode) {
#pragma unroll
        for (int e = 0; e < 8; ++e) cs[e] = colsum[c8 + e];
    }
    const int r0 = blockIdx.x * 16;
    for (int rr = 0; rr < 16; ++rr) {
        const int r = r0 + rr;
        u16x8 xv = *(const u16x8*)(buf + (size_t)r * 2048 + c8);
        float u[8];
        float s2 = 0.f, s4 = 0.f;
#pragma unroll
        for (int e = 0; e < 8; ++e) {
            float uu = fmaxf(b2f(xv[e]), 0.f) + EPSF;
            u[e] = uu;
            float q2 = uu * uu;
            s2 += q2;
            s4 += q2 * q2;
        }
#pragma unroll
        for (int m = 1; m <= 16; m <<= 1) {
            s2 += __shfl_xor(s2, m, 64);
            s4 += __shfl_xor(s4, m, 64);
        }
        const float sc = sqrtf(s2) / (c * sqrtf(s4));
        float ph[8];
#pragma unroll
        for (int e = 0; e < 8; ++e) ph[e] = u[e] * u[e] * sc;
        u16x8 ov;
        if (mode) {
            float den = 0.f;
#pragma unroll
            for (int e = 0; e < 8; ++e) den += ph[e] * cs[e];
#pragma unroll
            for (int m = 1; m <= 16; m <<= 1) den += __shfl_xor(den, m, 64);
            const float invd = 1.f / (den + EPSF);
#pragma unroll
            for (int e = 0; e < 8; ++e) ov[e] = f2b(ph[e] * invd);
        } else {
#pragma unroll
            for (int e = 0; e < 8; ++e) { ov[e] = f2b(ph[e]); csum[e] += ph[e]; }
        }
        *(u16x8*)(buf + (size_t)r * 2048 + c8) = ov;
    }
    if (!mode) {
#pragma unroll
        for (int e = 0; e < 8; ++e) atomicAdd(&colsum[c8 + e], csum[e]);
    }
}

// ---------------- ktv MFMA: ktv[h] += phiK_h^T @ vs_h ----------------
// grid (8, 8): x = split(2)*4 + tile(2x2 of 128x128); k = n (split 1024 rows)
__global__ __launch_bounds__(256) void ktv_mfma(
    const unsigned short* __restrict__ phiK,
    const unsigned short* __restrict__ vsb,
    float* __restrict__ ktv)
{
    __shared__ __align__(16) unsigned short lA[32 * 140];
    __shared__ __align__(16) unsigned short lB[32 * 140];
    const int t = threadIdx.x;
    const int h = blockIdx.y;
    const int split = blockIdx.x >> 2;
    const int tile = blockIdx.x & 3;
    const int m0 = (tile >> 1) * 128, d0 = (tile & 1) * 128;
    const int chh = h * 256;
    const int lane = t & 63, w = t >> 6;
    const int wm = (w >> 1) * 64, wn = (w & 1) * 64;
    const int l15 = lane & 15, q8 = (lane >> 4) * 8;

    f32x4 acc[4][4] = {};
    const int nbeg = split * 1024;
    for (int n0 = nbeg; n0 < nbeg + 1024; n0 += 32) {
#pragma unroll
        for (int qq = 0; qq < 2; ++qq) {
            const int e = t + qq * 256;
            const int row = e >> 4, cg = (e & 15) * 8;
            *(u16x8*)(&lA[row * 140 + cg]) =
                *(const u16x8*)(phiK + (size_t)(n0 + row) * 2048 + chh + m0 + cg);
            *(u16x8*)(&lB[row * 140 + cg]) =
                *(const u16x8*)(vsb + (size_t)(n0 + row) * 2048 + chh + d0 + cg);
        }
        __syncthreads();
        union { bf16x8 v; unsigned short s[8]; } af[4], bfr[4];
#pragma unroll
        for (int i = 0; i < 4; ++i)
#pragma unroll
            for (int jj = 0; jj < 8; ++jj)
                af[i].s[jj] = lA[(q8 + jj) * 140 + wm + i * 16 + l15];
#pragma unroll
        for (int j = 0; j < 4; ++j)
#pragma unroll
            for (int jj = 0; jj < 8; ++jj)
                bfr[j].s[jj] = lB[(q8 + jj) * 140 + wn + j * 16 + l15];
#pragma unroll
        for (int i = 0; i < 4; ++i)
#pragma unroll
            for (int j = 0; j < 4; ++j)
                acc[i][j] = __builtin_amdgcn_mfma_f32_16x16x32_bf16(af[i].v, bfr[j].v, acc[i][j], 0, 0, 0);
        __syncthreads();
    }
#pragma unroll
    for (int i = 0; i < 4; ++i)
#pragma unroll
        for (int j = 0; j < 4; ++j)
#pragma unroll
            for (int r = 0; r < 4; ++r) {
                const int m = m0 + wm + i * 16 + (lane >> 4) * 4 + r;
                const int d = d0 + wn + j * 16 + l15;
                atomicAdd(&ktv[((size_t)chh + m) * 256 + d], acc[i][j][r]);
            }
}

// ---------------- final MFMA GEMM: out[n][d] (+)= A[n][k&2047] . W2T[d][k] ----------------
// grid (CH/64, 4). accumulate=0: plain store; 1: read-add.
__global__ __launch_bounds__(256) void final_mfma(
    const unsigned short* __restrict__ Abuf,
    const unsigned short* __restrict__ W2T,
    int kbeg, int kend, int accumulate,
    float* __restrict__ outp)
{
    __shared__ __align__(16) unsigned short lA[64 * 40];
    __shared__ __align__(16) unsigned short lB[64 * 40];
    const int t = threadIdx.x;
    const int n0 = blockIdx.x * 64;
    const int d0 = blockIdx.y * 64;
    const int lane = t & 63, w = t >> 6;
    const int wm = (w >> 1) * 32, wn = (w & 1) * 32;
    const int l15 = lane & 15, q = lane >> 4;

    f32x4 acc[2][2] = {};
    for (int k0 = kbeg; k0 < kend; k0 += 32) {
        {
            const int row = t >> 2, kg = (t & 3) * 8;
            const int ka = (k0 + kg) & 2047;
            *(u16x8*)(&lA[row * 40 + kg]) =
                *(const u16x8*)(Abuf + (size_t)(n0 + row) * 2048 + ka);
            *(u16x8*)(&lB[row * 40 + kg]) =
                *(const u16x8*)(W2T + (size_t)(d0 + row) * 6144 + k0 + kg);
        }
        __syncthreads();
        bf16x8 af[2], bfr[2];
#pragma unroll
        for (int i = 0; i < 2; ++i)
            af[i] = *(const bf16x8*)(&lA[(wm + i * 16 + l15) * 40 + q * 8]);
#pragma unroll
        for (int j = 0; j < 2; ++j)
            bfr[j] = *(const bf16x8*)(&lB[(wn + j * 16 + l15) * 40 + q * 8]);
#pragma unroll
        for (int i = 0; i < 2; ++i)
#pragma unroll
            for (int j = 0; j < 2; ++j)
                acc[i][j] = __builtin_amdgcn_mfma_f32_16x16x32_bf16(af[i], bfr[j], acc[i][j], 0, 0, 0);
        __syncthreads();
    }
#pragma unroll
    for (int i = 0; i < 2; ++i)
#pragma unroll
        for (int j = 0; j < 2; ++j)
#pragma unroll
            for (int r = 0; r < 4; ++r) {
                const int n = n0 + wm + i * 16 + q * 4 + r;
                const int d = d0 + wn + j * 16 + l15;
                float* p = &outp[(size_t)n * 257 + 1 + d];
                if (accumulate) *p += acc[i][j][r];
                else            *p  = acc[i][j][r];
            }
}

// ---------------- W2T lower (G hi/lo) + bias2 ----------------
__global__ __launch_bounds__(256) void w2g_kernel(
    const float* __restrict__ vmw, const float* __restrict__ vmb,
    const float* __restrict__ fw,  const float* __restrict__ fb,
    unsigned short* __restrict__ W2T, float* __restrict__ bias2)
{
    const int t = threadIdx.x;
    if (blockIdx.x == 64) {
        float s = fb[t];
        for (int j = 0; j < 2048; ++j) s += vmb[j & 255] * fw[(size_t)t * 2048 + j];
        bias2[t] = s;
        return;
    }
    const int h = blockIdx.x >> 3;
    const int i0 = (blockIdx.x & 7) * 32;

    __shared__ __align__(16) float xlds[16][40];
    __shared__ float wlds[256][17];

    float acc[32];
#pragma unroll
    for (int r = 0; r < 32; ++r) acc[r] = 0.f;

    const int ar = t >> 3;
    const int ak = (t & 7) * 2;
    const int wk = t & 15;
    const int wo = (t >> 4) * 16;

    for (int d0 = 0; d0 < 256; d0 += 16) {
        xlds[ak][ar]     = vmw[(size_t)(d0 + ak) * 256 + i0 + ar];
        xlds[ak + 1][ar] = vmw[(size_t)(d0 + ak + 1) * 256 + i0 + ar];
#pragma unroll
        for (int j = 0; j < 16; ++j)
            wlds[wo + j][wk] = fw[(size_t)(wo + j) * 2048 + h * 256 + d0 + wk];
        __syncthreads();
#pragma unroll
        for (int kk = 0; kk < 16; ++kk) {
            float bv = wlds[t][kk];
            const float4* xr = (const float4*)(&xlds[kk][0]);
#pragma unroll
            for (int g = 0; g < 8; ++g) {
                float4 xv = xr[g];
                acc[g * 4 + 0] = fmaf(xv.x, bv, acc[g * 4 + 0]);
                acc[g * 4 + 1] = fmaf(xv.y, bv, acc[g * 4 + 1]);
                acc[g * 4 + 2] = fmaf(xv.z, bv, acc[g * 4 + 2]);
                acc[g * 4 + 3] = fmaf(xv.w, bv, acc[g * 4 + 3]);
            }
        }
        __syncthreads();
    }
#pragma unroll
    for (int r = 0; r < 32; ++r) {
        const float g = acc[r];
        const unsigned short hi = f2b(g);
        const unsigned short lo = f2b(g - b2f(hi));
        const int kk = h * 256 + i0 + r;
        W2T[(size_t)t * 6144 + 2048 + kk] = hi;
        W2T[(size_t)t * 6144 + 4096 + kk] = lo;
    }
}

// ---------------- W2T upper = ktv_h @ F_h^T (bf16) ----------------
__global__ __launch_bounds__(256) void w2u_kernel(
    const float* __restrict__ ktv,
    const float* __restrict__ fw,
    unsigned short* __restrict__ W2T)
{
    const int t = threadIdx.x;
    const int h = blockIdx.x >> 3;
    const int m0 = (blockIdx.x & 7) * 32;

    __shared__ __align__(16) float xlds[16][40];
    __shared__ float wlds[256][17];

    float acc[32];
#pragma unroll
    for (int r = 0; r < 32; ++r) acc[r] = 0.f;

    const int ar = t >> 3;
    const int ak = (t & 7) * 2;
    const int wk = t & 15;
    const int wo = (t >> 4) * 16;

    for (int d0 = 0; d0 < 256; d0 += 16) {
        {
            const float* src = ktv + (size_t)(h * 256 + m0 + ar) * 256 + d0 + ak;
            xlds[ak][ar]     = src[0];
            xlds[ak + 1][ar] = src[1];
        }
#pragma unroll
        for (int j = 0; j < 16; ++j)
            wlds[wo + j][wk] = fw[(size_t)(wo + j) * 2048 + h * 256 + d0 + wk];
        __syncthreads();
#pragma unroll
        for (int kk = 0; kk < 16; ++kk) {
            float bv = wlds[t][kk];
            const float4* xr = (const float4*)(&xlds[kk][0]);
#pragma unroll
            for (int g = 0; g < 8; ++g) {
                float4 xv = xr[g];
                acc[g * 4 + 0] = fmaf(xv.x, bv, acc[g * 4 + 0]);
                acc[g * 4 + 1] = fmaf(xv.y, bv, acc[g * 4 + 1]);
                acc[g * 4 + 2] = fmaf(xv.z, bv, acc[g * 4 + 2]);
                acc[g * 4 + 3] = fmaf(xv.w, bv, acc[g * 4 + 3]);
            }
        }
        __syncthreads();
    }
#pragma unroll
    for (int r = 0; r < 32; ++r)
        W2T[(size_t)t * 6144 + h * 256 + m0 + r] = f2b(acc[r]);
}

// ---------------- epilogue: bias + Lorentz lift ----------------
__global__ __launch_bounds__(256) void lift_kernel(
    const float* __restrict__ bias2, float* __restrict__ outp)
{
    const int t = threadIdx.x;
    const int lane = t & 63;
    const int w = t >> 6;
    const int n0 = blockIdx.x * 64 + w * 16;
    float b[4];
#pragma unroll
    for (int j = 0; j < 4; ++j) b[j] = bias2[lane + j * 64];
    for (int r = 0; r < 16; ++r) {
        float* row = outp + (size_t)(n0 + r) * 257;
        float v[4];
        float s = 0.f;
#pragma unroll
        for (int j = 0; j < 4; ++j) {
            v[j] = row[1 + lane + j * 64] + b[j];
            s = fmaf(v[j], v[j], s);
        }
#pragma unroll
        for (int off = 32; off > 0; off >>= 1) s += __shfl_down(s, off, 64);
#pragma unroll
        for (int j = 0; j < 4; ++j) row[1 + lane + j * 64] = v[j];
        if (lane == 0) row[0] = sqrtf(s + 1.0f);
    }
}

extern "C" void kernel_launch(void* const* d_in, const int* in_sizes, int n_in,
                              void* d_out, int out_size, void* d_ws, size_t ws_size,
                              hipStream_t stream)
{
    const float* xq  = (const float*)d_in[0];
    const float* xs  = (const float*)d_in[1];
    const float* Wq  = (const float*)d_in[2];
    const float* Bq  = (const float*)d_in[3];
    const float* Wk  = (const float*)d_in[4];
    const float* Bk  = (const float*)d_in[5];
    const float* Wv  = (const float*)d_in[6];
    const float* Bv  = (const float*)d_in[7];
    const float* nsc = (const float*)d_in[8];
    const float* vmw = (const float*)d_in[9];
    const float* vmb = (const float*)d_in[10];
    const float* fw  = (const float*)d_in[11];
    const float* fb  = (const float*)d_in[12];
    float* outp = (float*)d_out;

    char* ws = (char*)d_ws;
    // workspace layout (bytes), total ~25.5 MB
    float* ktv             = (float*)(ws + 0);                 // 2,097,152
    float* colsum          = (float*)(ws + 2097152);           //     8,192
    float* bias2           = (float*)(ws + 2105344);           //     1,024
    float* biasAll         = (float*)(ws + 2106368);           //    24,576
    unsigned short* W2T    = (unsigned short*)(ws + 2130944);  // 3,145,728
    unsigned short* Wbf    = (unsigned short*)(ws + 5276672);  // 3,538,944
    unsigned short* Xbf    = (unsigned short*)(ws + 8815616);  // 1,179,648
    unsigned short* phibuf = (unsigned short*)(ws + 9995264);  // 8,388,608
    unsigned short* vsbuf  = (unsigned short*)(ws + 18383872); // 8,388,608

    // zero ktv + colsum (contiguous 526336 floats)
    zero_kernel<<<dim3(2056), 256, 0, stream>>>(ktv, 526336);
    wconv_kernel<<<dim3(6168), 256, 0, stream>>>(Wq, Wk, Wv, Bq, Bk, Bv, Wbf, biasAll);
    w2g_kernel<<<dim3(65), 256, 0, stream>>>(vmw, vmb, fw, fb, W2T, bias2);

    // Pass A: K/V chunks -> phiK, colsum, ktv, out = vs @ [G_hi;G_lo]
    for (int c = 0; c < NCHK; ++c) {
        const float* xs_c = xs + (size_t)c * CH * 257;
        float* out_c = outp + (size_t)c * CH * 257;
        xconv_kernel<<<dim3(256), 256, 0, stream>>>(xs_c, Xbf);
        proj_mfma<<<dim3(16, 32), 256, 0, stream>>>(
            Xbf, Wbf + (size_t)2048 * 288, biasAll + 2048, phibuf, vsbuf, 2048);
        phi_kernel<<<dim3(128), 256, 0, stream>>>(phibuf, nsc, colsum, 0);
        ktv_mfma<<<dim3(8, 8), 256, 0, stream>>>(phibuf, vsbuf, ktv);
        final_mfma<<<dim3(32, 4), 256, 0, stream>>>(vsbuf, W2T, 2048, 6144, 0, out_c);
    }

    // ktv-dependent weights
    w2u_kernel<<<dim3(64), 256, 0, stream>>>(ktv, fw, W2T);

    // Pass B: Q chunks -> phiQ*invden, out += phiQs @ W2u
    for (int c = 0; c < NCHK; ++c) {
        const float* xq_c = xq + (size_t)c * CH * 257;
        float* out_c = outp + (size_t)c * CH * 257;
        xconv_kernel<<<dim3(256), 256, 0, stream>>>(xq_c, Xbf);
        proj_mfma<<<dim3(16, 16), 256, 0, stream>>>(
            Xbf, Wbf, biasAll, phibuf, phibuf, 4096);
        phi_kernel<<<dim3(128), 256, 0, stream>>>(phibuf, nsc, colsum, 1);
        final_mfma<<<dim3(32, 4), 256, 0, stream>>>(phibuf, W2T, 0, 2048, 1, out_c);
    }

    // bias + Lorentz lift
    lift_kernel<<<dim3(512), 256, 0, stream>>>(bias2, outp);
}

// Round 5
// 1766.284 us; speedup vs baseline: 7.3736x; 2.0879x over previous
//
#include <hip/hip_runtime.h>
#include <hip/hip_bf16.h>

// DHHT round 5: dispatch-count + tail fixes.
//  - dynamic chunk size (8192/4096/2048) selected from ws_size
//  - xconv fused into proj staging (reads fp32 X directly)
//  - ktv: transposed LDS staging -> b128 frag reads (was 128 scalar reads/lane)
//  - bias2 split out of w2g (256-block coalesced reduction)
//  - G_lo compensation dropped (G precision not the error driver)
//  - final_mfma retiled 128x64
// W2T bf16 [256][4096]: cols 0..2047 = W2u (ktv@F^T), 2048..4095 = G.

#define EPSF 1e-6f

typedef __attribute__((ext_vector_type(8))) short bf16x8;
typedef __attribute__((ext_vector_type(8))) unsigned short u16x8;
typedef __attribute__((ext_vector_type(4))) float f32x4;
typedef float f32x4a __attribute__((ext_vector_type(4), aligned(4)));

__device__ __forceinline__ float b2f(unsigned short u) {
    union { unsigned int i; float f; } c;
    c.i = ((unsigned int)u) << 16;
    return c.f;
}
__device__ __forceinline__ unsigned short f2b(float f) {
    __hip_bfloat16 h = __float2bfloat16(f);
    union { __hip_bfloat16 h; unsigned short u; } c;
    c.h = h;
    return c.u;
}

__global__ void zero_kernel(float* __restrict__ p, int n) {
    int i = blockIdx.x * 256 + threadIdx.x;
    if (i < n) p[i] = 0.f;
}

// ---------------- weight convert: Wbf [6144][288] bf16 + biasAll[6144] ----------------
__global__ __launch_bounds__(256) void wconv_kernel(
    const float* __restrict__ Wq, const float* __restrict__ Wk, const float* __restrict__ Wv,
    const float* __restrict__ Bq, const float* __restrict__ Bk, const float* __restrict__ Bv,
    unsigned short* __restrict__ Wbf, float* __restrict__ biasAll)
{
    const int t = threadIdx.x;
    const int b = blockIdx.x;
    if (b < 6144) {
        const int mat = b >> 11, lr = b & 2047;
        const float* Ws = (mat == 0 ? Wq : mat == 1 ? Wk : Wv) + (size_t)lr * 257;
        Wbf[(size_t)b * 288 + t] = f2b(Ws[t]);
        if (t < 32) {
            float v = (t == 0) ? Ws[256] : 0.f;
            Wbf[(size_t)b * 288 + 256 + t] = f2b(v);
        }
    } else {
        const int e = (b - 6144) * 256 + t;
        const int mat = e >> 11, r = e & 2047;
        biasAll[e] = (mat == 0 ? Bq : mat == 1 ? Bk : Bv)[r];
    }
}

// ---------------- projection MFMA GEMM: X fp32 [rows][257] @ Wbf[cols][288]^T ----------------
// grid (rows/128, cols/128). Output bf16 + bias. col<splitCol -> outA else outB[col-2048].
__global__ __launch_bounds__(256) void proj_mfma(
    const float* __restrict__ X,
    const unsigned short* __restrict__ Wbase,
    const float* __restrict__ biasBase,
    unsigned short* __restrict__ outA,
    unsigned short* __restrict__ outB,
    int splitCol)
{
    __shared__ __align__(16) unsigned short lA[128 * 40];
    __shared__ __align__(16) unsigned short lB[128 * 40];
    const int t = threadIdx.x;
    const int m0 = blockIdx.x * 128;
    const int c0 = blockIdx.y * 128;
    const int lane = t & 63, w = t >> 6;
    const int wm = (w >> 1) * 64, wn = (w & 1) * 64;
    const int l15 = lane & 15, q = lane >> 4;

    f32x4 acc[4][4] = {};

    for (int ks = 0; ks < 9; ++ks) {
        const int k0 = ks * 32;
        if (ks < 8) {
            // A: 128 rows x 32 k fp32 -> bf16
#pragma unroll
            for (int qq = 0; qq < 4; ++qq) {
                const int e = t + qq * 256;
                const int row = e >> 3, kg = (e & 7) * 4;
                f32x4a xv = *(const f32x4a*)(X + (size_t)(m0 + row) * 257 + k0 + kg);
                unsigned short* d = &lA[row * 40 + kg];
                d[0] = f2b(xv[0]); d[1] = f2b(xv[1]);
                d[2] = f2b(xv[2]); d[3] = f2b(xv[3]);
            }
        } else {
            // k 256..287: only col 256 nonzero
#pragma unroll
            for (int qq = 0; qq < 2; ++qq) {
                const int e = t + qq * 256;
                const int row = e >> 2, part = e & 3;
                u16x8 z = {};
                if (part == 0) z[0] = f2b(X[(size_t)(m0 + row) * 257 + 256]);
                *(u16x8*)(&lA[row * 40 + part * 8]) = z;
            }
        }
#pragma unroll
        for (int qq = 0; qq < 2; ++qq) {
            const int e = t + qq * 256;
            const int row = e >> 2, kg = (e & 3) * 8;
            *(u16x8*)(&lB[row * 40 + kg]) =
                *(const u16x8*)(Wbase + (size_t)(c0 + row) * 288 + k0 + kg);
        }
        __syncthreads();
        bf16x8 af[4], bfr[4];
#pragma unroll
        for (int i = 0; i < 4; ++i)
            af[i] = *(const bf16x8*)(&lA[(wm + i * 16 + l15) * 40 + q * 8]);
#pragma unroll
        for (int j = 0; j < 4; ++j)
            bfr[j] = *(const bf16x8*)(&lB[(wn + j * 16 + l15) * 40 + q * 8]);
#pragma unroll
        for (int i = 0; i < 4; ++i)
#pragma unroll
            for (int j = 0; j < 4; ++j)
                acc[i][j] = __builtin_amdgcn_mfma_f32_16x16x32_bf16(af[i], bfr[j], acc[i][j], 0, 0, 0);
        __syncthreads();
    }

#pragma unroll
    for (int j = 0; j < 4; ++j) {
        const int cg = c0 + wn + j * 16 + l15;
        const float bias = biasBase[cg];
        unsigned short* dst;
        int cd;
        if (cg < splitCol) { dst = outA; cd = cg; }
        else               { dst = outB; cd = cg - 2048; }
#pragma unroll
        for (int i = 0; i < 4; ++i)
#pragma unroll
            for (int r = 0; r < 4; ++r) {
                const int n = m0 + wm + i * 16 + q * 4 + r;
                dst[(size_t)n * 2048 + cd] = f2b(acc[i][j][r] + bias);
            }
    }
}

// ---------------- phi (in-place on [CH][2048] bf16) ----------------
__global__ __launch_bounds__(256) void phi_kernel(
    unsigned short* __restrict__ buf,
    const float* __restrict__ nsc,
    float* __restrict__ colsum,
    int mode)
{
    const int t = threadIdx.x;
    const int c8 = t * 8;
    const float c = fabsf(nsc[0]) + EPSF;
    float cs[8], csum[8];
#pragma unroll
    for (int e = 0; e < 8; ++e) csum[e] = 0.f;
    if (mode) {
#pragma unroll
        for (int e = 0; e < 8; ++e) cs[e] = colsum[c8 + e];
    }
    const int r0 = blockIdx.x * 16;
    for (int rr = 0; rr < 16; ++rr) {
        const int r = r0 + rr;
        u16x8 xv = *(const u16x8*)(buf + (size_t)r * 2048 + c8);
        float u[8];
        float s2 = 0.f, s4 = 0.f;
#pragma unroll
        for (int e = 0; e < 8; ++e) {
            float uu = fmaxf(b2f(xv[e]), 0.f) + EPSF;
            u[e] = uu;
            float q2 = uu * uu;
            s2 += q2;
            s4 += q2 * q2;
        }
#pragma unroll
        for (int m = 1; m <= 16; m <<= 1) {
            s2 += __shfl_xor(s2, m, 64);
            s4 += __shfl_xor(s4, m, 64);
        }
        const float sc = sqrtf(s2) / (c * sqrtf(s4));
        float ph[8];
#pragma unroll
        for (int e = 0; e < 8; ++e) ph[e] = u[e] * u[e] * sc;
        u16x8 ov;
        if (mode) {
            float den = 0.f;
#pragma unroll
            for (int e = 0; e < 8; ++e) den += ph[e] * cs[e];
#pragma unroll
            for (int m = 1; m <= 16; m <<= 1) den += __shfl_xor(den, m, 64);
            const float invd = 1.f / (den + EPSF);
#pragma unroll
            for (int e = 0; e < 8; ++e) ov[e] = f2b(ph[e] * invd);
        } else {
#pragma unroll
            for (int e = 0; e < 8; ++e) { ov[e] = f2b(ph[e]); csum[e] += ph[e]; }
        }
        *(u16x8*)(buf + (size_t)r * 2048 + c8) = ov;
    }
    if (!mode) {
#pragma unroll
        for (int e = 0; e < 8; ++e) atomicAdd(&colsum[c8 + e], csum[e]);
    }
}

// ---------------- ktv MFMA: ktv[h] += phiK_h^T @ vs_h ----------------
// grid ((CH/512)*4, 8). Transposed LDS staging -> b128 frag reads.
__global__ __launch_bounds__(256) void ktv_mfma(
    const unsigned short* __restrict__ phiK,
    const unsigned short* __restrict__ vsb,
    float* __restrict__ ktv)
{
    __shared__ __align__(16) unsigned short lAT[128 * 40];  // [m][n] transposed
    __shared__ __align__(16) unsigned short lBT[128 * 40];  // [d][n]
    const int t = threadIdx.x;
    const int h = blockIdx.y;
    const int split = blockIdx.x >> 2;
    const int tile = blockIdx.x & 3;
    const int m0 = (tile >> 1) * 128, d0 = (tile & 1) * 128;
    const int chh = h * 256;
    const int lane = t & 63, w = t >> 6;
    const int wm = (w >> 1) * 64, wn = (w & 1) * 64;
    const int l15 = lane & 15, q8 = (lane >> 4) * 8;

    f32x4 acc[4][4] = {};
    const int nbeg = split * 512;
    for (int n0 = nbeg; n0 < nbeg + 512; n0 += 32) {
#pragma unroll
        for (int qq = 0; qq < 2; ++qq) {
            const int e = t + qq * 256;
            const int row = e >> 4, cg = (e & 15) * 8;
            u16x8 a = *(const u16x8*)(phiK + (size_t)(n0 + row) * 2048 + chh + m0 + cg);
            u16x8 b = *(const u16x8*)(vsb  + (size_t)(n0 + row) * 2048 + chh + d0 + cg);
#pragma unroll
            for (int j = 0; j < 8; ++j) {
                lAT[(cg + j) * 40 + row] = a[j];
                lBT[(cg + j) * 40 + row] = b[j];
            }
        }
        __syncthreads();
        bf16x8 af[4], bfr[4];
#pragma unroll
        for (int i = 0; i < 4; ++i)
            af[i] = *(const bf16x8*)(&lAT[(wm + i * 16 + l15) * 40 + q8]);
#pragma unroll
        for (int j = 0; j < 4; ++j)
            bfr[j] = *(const bf16x8*)(&lBT[(wn + j * 16 + l15) * 40 + q8]);
#pragma unroll
        for (int i = 0; i < 4; ++i)
#pragma unroll
            for (int j = 0; j < 4; ++j)
                acc[i][j] = __builtin_amdgcn_mfma_f32_16x16x32_bf16(af[i], bfr[j], acc[i][j], 0, 0, 0);
        __syncthreads();
    }
#pragma unroll
    for (int i = 0; i < 4; ++i)
#pragma unroll
        for (int j = 0; j < 4; ++j)
#pragma unroll
            for (int r = 0; r < 4; ++r) {
                const int m = m0 + wm + i * 16 + (lane >> 4) * 4 + r;
                const int d = d0 + wn + j * 16 + l15;
                atomicAdd(&ktv[((size_t)chh + m) * 256 + d], acc[i][j][r]);
            }
}

// ---------------- final MFMA GEMM 128x64: out[n][d] (+)= A[n][k&2047].W2T[d][k] ----------------
// grid (CH/128, 4). accumulate=0: store; 1: read-add.
__global__ __launch_bounds__(256) void final_mfma(
    const unsigned short* __restrict__ Abuf,
    const unsigned short* __restrict__ W2T,
    int kbeg, int kend, int accumulate,
    float* __restrict__ outp)
{
    __shared__ __align__(16) unsigned short lA[128 * 40];
    __shared__ __align__(16) unsigned short lB[64 * 40];
    const int t = threadIdx.x;
    const int n0 = blockIdx.x * 128;
    const int d0 = blockIdx.y * 64;
    const int lane = t & 63, w = t >> 6;
    const int wm = w * 32;
    const int l15 = lane & 15, q = lane >> 4;

    f32x4 acc[2][4] = {};
    for (int k0 = kbeg; k0 < kend; k0 += 32) {
#pragma unroll
        for (int qq = 0; qq < 2; ++qq) {
            const int e = t + qq * 256;
            const int row = e >> 2, kg = (e & 3) * 8;
            *(u16x8*)(&lA[row * 40 + kg]) =
                *(const u16x8*)(Abuf + (size_t)(n0 + row) * 2048 + ((k0 + kg) & 2047));
        }
        {
            const int row = t >> 2, kg = (t & 3) * 8;
            *(u16x8*)(&lB[row * 40 + kg]) =
                *(const u16x8*)(W2T + (size_t)(d0 + row) * 4096 + k0 + kg);
        }
        __syncthreads();
        bf16x8 af[2], bfr[4];
#pragma unroll
        for (int i = 0; i < 2; ++i)
            af[i] = *(const bf16x8*)(&lA[(wm + i * 16 + l15) * 40 + q * 8]);
#pragma unroll
        for (int j = 0; j < 4; ++j)
            bfr[j] = *(const bf16x8*)(&lB[(j * 16 + l15) * 40 + q * 8]);
#pragma unroll
        for (int i = 0; i < 2; ++i)
#pragma unroll
            for (int j = 0; j < 4; ++j)
                acc[i][j] = __builtin_amdgcn_mfma_f32_16x16x32_bf16(af[i], bfr[j], acc[i][j], 0, 0, 0);
        __syncthreads();
    }
#pragma unroll
    for (int i = 0; i < 2; ++i)
#pragma unroll
        for (int j = 0; j < 4; ++j)
#pragma unroll
            for (int r = 0; r < 4; ++r) {
                const int n = n0 + wm + i * 16 + q * 4 + r;
                const int d = d0 + j * 16 + l15;
                float* p = &outp[(size_t)n * 257 + 1 + d];
                if (accumulate) *p += acc[i][j][r];
                else            *p  = acc[i][j][r];
            }
}

// ---------------- W2T G part: G_h = vmw^T F_h^T ----------------
__global__ __launch_bounds__(256) void w2g_kernel(
    const float* __restrict__ vmw,
    const float* __restrict__ fw,
    unsigned short* __restrict__ W2T)
{
    const int t = threadIdx.x;
    const int h = blockIdx.x >> 3;
    const int i0 = (blockIdx.x & 7) * 32;

    __shared__ __align__(16) float xlds[16][40];
    __shared__ float wlds[256][17];

    float acc[32];
#pragma unroll
    for (int r = 0; r < 32; ++r) acc[r] = 0.f;

    const int ar = t >> 3;
    const int ak = (t & 7) * 2;
    const int wk = t & 15;
    const int wo = (t >> 4) * 16;

    for (int d0 = 0; d0 < 256; d0 += 16) {
        xlds[ak][ar]     = vmw[(size_t)(d0 + ak) * 256 + i0 + ar];
        xlds[ak + 1][ar] = vmw[(size_t)(d0 + ak + 1) * 256 + i0 + ar];
#pragma unroll
        for (int j = 0; j < 16; ++j)
            wlds[wo + j][wk] = fw[(size_t)(wo + j) * 2048 + h * 256 + d0 + wk];
        __syncthreads();
#pragma unroll
        for (int kk = 0; kk < 16; ++kk) {
            float bv = wlds[t][kk];
            const float4* xr = (const float4*)(&xlds[kk][0]);
#pragma unroll
            for (int g = 0; g < 8; ++g) {
                float4 xv = xr[g];
                acc[g * 4 + 0] = fmaf(xv.x, bv, acc[g * 4 + 0]);
                acc[g * 4 + 1] = fmaf(xv.y, bv, acc[g * 4 + 1]);
                acc[g * 4 + 2] = fmaf(xv.z, bv, acc[g * 4 + 2]);
                acc[g * 4 + 3] = fmaf(xv.w, bv, acc[g * 4 + 3]);
            }
        }
        __syncthreads();
    }
#pragma unroll
    for (int r = 0; r < 32; ++r)
        W2T[(size_t)t * 4096 + 2048 + h * 256 + i0 + r] = f2b(acc[r]);
}

// ---------------- bias2[o] = fb[o] + sum_j vmb[j&255]*fw[o*2048+j] ----------------
__global__ __launch_bounds__(256) void bias2_kernel(
    const float* __restrict__ vmb, const float* __restrict__ fw,
    const float* __restrict__ fb, float* __restrict__ bias2)
{
    const int o = blockIdx.x;
    const int t = threadIdx.x;
    float s = 0.f;
#pragma unroll
    for (int i = 0; i < 8; ++i)
        s += fw[(size_t)o * 2048 + t + i * 256];
    s *= vmb[t];
#pragma unroll
    for (int off = 32; off > 0; off >>= 1) s += __shfl_down(s, off, 64);
    __shared__ float r4[4];
    if ((t & 63) == 0) r4[t >> 6] = s;
    __syncthreads();
    if (t == 0) bias2[o] = fb[o] + r4[0] + r4[1] + r4[2] + r4[3];
}

// ---------------- W2T upper = ktv_h @ F_h^T (bf16) ----------------
__global__ __launch_bounds__(256) void w2u_kernel(
    const float* __restrict__ ktv,
    const float* __restrict__ fw,
    unsigned short* __restrict__ W2T)
{
    const int t = threadIdx.x;
    const int h = blockIdx.x >> 3;
    const int m0 = (blockIdx.x & 7) * 32;

    __shared__ __align__(16) float xlds[16][40];
    __shared__ float wlds[256][17];

    float acc[32];
#pragma unroll
    for (int r = 0; r < 32; ++r) acc[r] = 0.f;

    const int ar = t >> 3;
    const int ak = (t & 7) * 2;
    const int wk = t & 15;
    const int wo = (t >> 4) * 16;

    for (int d0 = 0; d0 < 256; d0 += 16) {
        {
            const float* src = ktv + (size_t)(h * 256 + m0 + ar) * 256 + d0 + ak;
            xlds[ak][ar]     = src[0];
            xlds[ak + 1][ar] = src[1];
        }
#pragma unroll
        for (int j = 0; j < 16; ++j)
            wlds[wo + j][wk] = fw[(size_t)(wo + j) * 2048 + h * 256 + d0 + wk];
        __syncthreads();
#pragma unroll
        for (int kk = 0; kk < 16; ++kk) {
            float bv = wlds[t][kk];
            const float4* xr = (const float4*)(&xlds[kk][0]);
#pragma unroll
            for (int g = 0; g < 8; ++g) {
                float4 xv = xr[g];
                acc[g * 4 + 0] = fmaf(xv.x, bv, acc[g * 4 + 0]);
                acc[g * 4 + 1] = fmaf(xv.y, bv, acc[g * 4 + 1]);
                acc[g * 4 + 2] = fmaf(xv.z, bv, acc[g * 4 + 2]);
                acc[g * 4 + 3] = fmaf(xv.w, bv, acc[g * 4 + 3]);
            }
        }
        __syncthreads();
    }
#pragma unroll
    for (int r = 0; r < 32; ++r)
        W2T[(size_t)t * 4096 + h * 256 + m0 + r] = f2b(acc[r]);
}

// ---------------- epilogue: bias + Lorentz lift ----------------
__global__ __launch_bounds__(256) void lift_kernel(
    const float* __restrict__ bias2, float* __restrict__ outp)
{
    const int t = threadIdx.x;
    const int lane = t & 63;
    const int w = t >> 6;
    const int n0 = blockIdx.x * 64 + w * 16;
    float b[4];
#pragma unroll
    for (int j = 0; j < 4; ++j) b[j] = bias2[lane + j * 64];
    for (int r = 0; r < 16; ++r) {
        float* row = outp + (size_t)(n0 + r) * 257;
        float v[4];
        float s = 0.f;
#pragma unroll
        for (int j = 0; j < 4; ++j) {
            v[j] = row[1 + lane + j * 64] + b[j];
            s = fmaf(v[j], v[j], s);
        }
#pragma unroll
        for (int off = 32; off > 0; off >>= 1) s += __shfl_down(s, off, 64);
#pragma unroll
        for (int j = 0; j < 4; ++j) row[1 + lane + j * 64] = v[j];
        if (lane == 0) row[0] = sqrtf(s + 1.0f);
    }
}

extern "C" void kernel_launch(void* const* d_in, const int* in_sizes, int n_in,
                              void* d_out, int out_size, void* d_ws, size_t ws_size,
                              hipStream_t stream)
{
    const float* xq  = (const float*)d_in[0];
    const float* xs  = (const float*)d_in[1];
    const float* Wq  = (const float*)d_in[2];
    const float* Bq  = (const float*)d_in[3];
    const float* Wk  = (const float*)d_in[4];
    const float* Bk  = (const float*)d_in[5];
    const float* Wv  = (const float*)d_in[6];
    const float* Bv  = (const float*)d_in[7];
    const float* nsc = (const float*)d_in[8];
    const float* vmw = (const float*)d_in[9];
    const float* vmb = (const float*)d_in[10];
    const float* fw  = (const float*)d_in[11];
    const float* fb  = (const float*)d_in[12];
    float* outp = (float*)d_out;

    char* ws = (char*)d_ws;
    // fixed workspace: 7,767,040 bytes
    float* ktv          = (float*)(ws + 0);                // 2,097,152
    float* colsum       = (float*)(ws + 2097152);          //     8,192
    float* bias2        = (float*)(ws + 2105344);          //     1,024
    float* biasAll      = (float*)(ws + 2106368);          //    24,576
    unsigned short* W2T = (unsigned short*)(ws + 2130944); // 2,097,152
    unsigned short* Wbf = (unsigned short*)(ws + 4228096); // 3,538,944
    const size_t fixedBytes = 7767040;

    // dynamic chunk size: phibuf + vsbuf = CH*8192 bytes
    int CH = 2048;
    if (ws_size >= fixedBytes + (size_t)8192 * 8192) CH = 8192;
    else if (ws_size >= fixedBytes + (size_t)4096 * 8192) CH = 4096;
    const int NCHK = 32768 / CH;
    unsigned short* phibuf = (unsigned short*)(ws + fixedBytes);
    unsigned short* vsbuf  = (unsigned short*)(ws + fixedBytes + (size_t)CH * 4096);

    zero_kernel<<<dim3(2056), 256, 0, stream>>>(ktv, 526336);
    wconv_kernel<<<dim3(6168), 256, 0, stream>>>(Wq, Wk, Wv, Bq, Bk, Bv, Wbf, biasAll);
    w2g_kernel<<<dim3(64), 256, 0, stream>>>(vmw, fw, W2T);
    bias2_kernel<<<dim3(256), 256, 0, stream>>>(vmb, fw, fb, bias2);

    // Pass A: K/V chunks -> phiK, colsum, ktv, out = vs @ G
    for (int c = 0; c < NCHK; ++c) {
        const float* xs_c = xs + (size_t)c * CH * 257;
        float* out_c = outp + (size_t)c * CH * 257;
        proj_mfma<<<dim3(CH / 128, 32), 256, 0, stream>>>(
            xs_c, Wbf + (size_t)2048 * 288, biasAll + 2048, phibuf, vsbuf, 2048);
        phi_kernel<<<dim3(CH / 16), 256, 0, stream>>>(phibuf, nsc, colsum, 0);
        ktv_mfma<<<dim3((CH / 512) * 4, 8), 256, 0, stream>>>(phibuf, vsbuf, ktv);
        final_mfma<<<dim3(CH / 128, 4), 256, 0, stream>>>(vsbuf, W2T, 2048, 4096, 0, out_c);
    }

    // ktv-dependent weights
    w2u_kernel<<<dim3(64), 256, 0, stream>>>(ktv, fw, W2T);

    // Pass B: Q chunks -> phiQ*invden, out += phiQs @ W2u
    for (int c = 0; c < NCHK; ++c) {
        const float* xq_c = xq + (size_t)c * CH * 257;
        float* out_c = outp + (size_t)c * CH * 257;
        proj_mfma<<<dim3(CH / 128, 16), 256, 0, stream>>>(
            xq_c, Wbf, biasAll, phibuf, phibuf, 4096);
        phi_kernel<<<dim3(CH / 16), 256, 0, stream>>>(phibuf, nsc, colsum, 1);
        final_mfma<<<dim3(CH / 128, 4), 256, 0, stream>>>(phibuf, W2T, 0, 2048, 1, out_c);
    }

    // bias + Lorentz lift
    lift_kernel<<<dim3(512), 256, 0, stream>>>(bias2, outp);
}